// Round 1
// baseline (196.267 us; speedup 1.0000x reference)
//
#include <hip/hip_runtime.h>
#include <hip/hip_bf16.h>
#include <cmath>

#define BH_N 32
#define SEQ  2048
#define DH   128
#define BM   64           // q rows per block
#define KT   64           // keys per tile
#define NTILES (SEQ / KT) // 32

typedef __attribute__((ext_vector_type(4))) float f32x4;
typedef __attribute__((ext_vector_type(8))) short bf16x8;
typedef __attribute__((ext_vector_type(4))) unsigned int u32x4;
typedef __attribute__((ext_vector_type(2))) unsigned int u32x2;

__device__ __forceinline__ unsigned short bfbits(float x) {
  unsigned u = __builtin_bit_cast(unsigned, x);
  u += 0x7fffu + ((u >> 16) & 1u);   // RNE
  return (unsigned short)(u >> 16);
}
__device__ __forceinline__ unsigned pk2(float x, float y) {
  return (unsigned)bfbits(x) | ((unsigned)bfbits(y) << 16);
}

// LDS map (40960 B):
//   [0,     16384): K_lds  [64 key][128 d] bf16, byte ^= (key&7)<<4
//   [16384, 32768): Vt_lds [128 d][64 key] bf16, byte ^= (d&7)<<4
//   [32768, 40960): P_lds per-wave 2KB: [16 q][64 key] bf16, byte ^= (q&7)<<4
// epilogue reuses [0,32768): per-wave 8KB O[16 q][128 d] f32, byte ^= (q&7)<<4

__global__ __launch_bounds__(256) void attn_fwd(
    const float* __restrict__ Kg, const float* __restrict__ Qg,
    const float* __restrict__ Vg, float* __restrict__ Og)
{
  __shared__ __align__(16) char lds[40960];
  constexpr float QSC = 0.08838834764831845f * 1.4426950408889634f; // 1/sqrt(128)*log2(e)

  const int t    = threadIdx.x;
  const int lane = t & 63;
  const int w    = t >> 6;
  const int g    = lane >> 4;
  const int q15  = lane & 15;

  const int bh   = blockIdx.x >> 5;
  const int qb   = blockIdx.x & 31;
  const int blkq = qb * BM;
  const size_t base = (size_t)bh * SEQ * DH;

  // ---- Q fragments (B-operand of St = K*Q^T), pre-scaled into exp2 domain
  bf16x8 qf[4];
  {
    const float* qp = Qg + base + (size_t)(blkq + w * 16 + q15) * DH;
    #pragma unroll
    for (int ks = 0; ks < 4; ++ks) {
      const float4 a = *(const float4*)(qp + ks * 32 + g * 8);
      const float4 b = *(const float4*)(qp + ks * 32 + g * 8 + 4);
      u32x4 u = { pk2(a.x * QSC, a.y * QSC), pk2(a.z * QSC, a.w * QSC),
                  pk2(b.x * QSC, b.y * QSC), pk2(b.z * QSC, b.w * QSC) };
      qf[ks] = __builtin_bit_cast(bf16x8, u);
    }
  }

  f32x4 ot[8];
  #pragma unroll
  for (int i = 0; i < 8; ++i) ot[i] = (f32x4){0.f, 0.f, 0.f, 0.f};

  float m_run = -INFINITY;
  float l_run = 0.f;

  for (int tile = 0; tile < NTILES; ++tile) {
    const int kb = tile * KT;
    __syncthreads();   // previous iteration's LDS reads complete

    // ---- stage K tile: coalesced 32B/lane global reads, b128 swizzled LDS writes
    #pragma unroll
    for (int i = 0; i < 4; ++i) {
      const int s   = t + 256 * i;
      const int key = s >> 4;
      const int d0  = (s & 15) * 8;
      const float* p = Kg + base + (size_t)(kb + key) * DH + d0;
      const float4 a = *(const float4*)p;
      const float4 b = *(const float4*)(p + 4);
      u32x4 u = { pk2(a.x, a.y), pk2(a.z, a.w), pk2(b.x, b.y), pk2(b.z, b.w) };
      const int off = (key * 256 + d0 * 2) ^ ((key & 7) << 4);
      *(u32x4*)(lds + off) = u;
    }
    // ---- stage V^T tile: dword-coalesced column gather (lanes = consecutive d)
    {
      const int dd = t & 127;
      const int kh = t >> 7;
      #pragma unroll
      for (int i = 0; i < 4; ++i) {
        const int key0 = kh * 32 + i * 8;
        const float* p = Vg + base + (size_t)(kb + key0) * DH + dd;
        float v0 = p[0 * DH], v1 = p[1 * DH], v2 = p[2 * DH], v3 = p[3 * DH];
        float v4 = p[4 * DH], v5 = p[5 * DH], v6 = p[6 * DH], v7 = p[7 * DH];
        u32x4 u = { pk2(v0, v1), pk2(v2, v3), pk2(v4, v5), pk2(v6, v7) };
        const int off = 16384 + ((dd * 128 + key0 * 2) ^ ((dd & 7) << 4));
        *(u32x4*)(lds + off) = u;
      }
    }
    __syncthreads();

    // ---- St = K * Q^T  (St[key][q], col=q=lane&15, row=key=kt*16+4g+reg)
    f32x4 st[4];
    #pragma unroll
    for (int kt = 0; kt < 4; ++kt) st[kt] = (f32x4){0.f, 0.f, 0.f, 0.f};
    #pragma unroll
    for (int kt = 0; kt < 4; ++kt) {
      const int key = kt * 16 + q15;
      const int row = key * 256;
      const int sw  = (key & 7) << 4;
      #pragma unroll
      for (int ks = 0; ks < 4; ++ks) {
        const bf16x8 kf = *(const bf16x8*)(lds + (row + ((ks * 64 + g * 16) ^ sw)));
        st[kt] = __builtin_amdgcn_mfma_f32_16x16x32_bf16(kf, qf[ks], st[kt], 0, 0, 0);
      }
    }

    // ---- online softmax (all stats in the q = lane&15 domain)
    float tm = st[0][0];
    #pragma unroll
    for (int kt = 0; kt < 4; ++kt)
      #pragma unroll
      for (int r = 0; r < 4; ++r) tm = fmaxf(tm, st[kt][r]);
    tm = fmaxf(tm, __shfl_xor(tm, 16));
    tm = fmaxf(tm, __shfl_xor(tm, 32));
    const float mnew = fmaxf(m_run, tm);
    const float rs   = exp2f(m_run - mnew);   // first tile: exp2(-inf)=0
    float psum = 0.f;
    #pragma unroll
    for (int kt = 0; kt < 4; ++kt)
      #pragma unroll
      for (int r = 0; r < 4; ++r) {
        const float p = exp2f(st[kt][r] - mnew);
        st[kt][r] = p;
        psum += p;
      }
    psum += __shfl_xor(psum, 16);
    psum += __shfl_xor(psum, 32);
    l_run = l_run * rs + psum;
    m_run = mnew;
    #pragma unroll
    for (int mt = 0; mt < 8; ++mt) {
      ot[mt][0] *= rs; ot[mt][1] *= rs; ot[mt][2] *= rs; ot[mt][3] *= rs;
    }

    // ---- P -> wave-private LDS (layout convert StT-frag -> PV B-frag)
    const int pb   = 32768 + w * 2048;
    const int prow = q15 * 128;
    const int psw  = (q15 & 7) << 4;
    #pragma unroll
    for (int kt = 0; kt < 4; ++kt) {
      u32x2 u = { pk2(st[kt][0], st[kt][1]), pk2(st[kt][2], st[kt][3]) };
      *(u32x2*)(lds + pb + (prow + ((kt * 32 + g * 8) ^ psw))) = u;
    }
    bf16x8 pf[2];
    #pragma unroll
    for (int k2 = 0; k2 < 2; ++k2)
      pf[k2] = *(const bf16x8*)(lds + pb + (prow + ((k2 * 64 + g * 16) ^ psw)));

    // ---- Ot += V^T * P^T   (Ot[d][q], col=q=lane&15)
    #pragma unroll
    for (int mt = 0; mt < 8; ++mt) {
      const int dl   = mt * 16 + q15;
      const int vrow = 16384 + dl * 128;
      const int vsw  = (dl & 7) << 4;
      #pragma unroll
      for (int k2 = 0; k2 < 2; ++k2) {
        const bf16x8 vf = *(const bf16x8*)(lds + (vrow + ((k2 * 64 + g * 16) ^ vsw)));
        ot[mt] = __builtin_amdgcn_mfma_f32_16x16x32_bf16(vf, pf[k2], ot[mt], 0, 0, 0);
      }
    }
  }

  // ---- epilogue: normalize, transpose Ot via LDS, coalesced fp32 store
  __syncthreads();   // all waves done reading K/Vt regions
  const float rcp = 1.0f / l_run;
  const int ob = w * 8192;
  {
    const int orow = q15 * 512;
    const int osw  = (q15 & 7) << 4;
    #pragma unroll
    for (int mt = 0; mt < 8; ++mt) {
      f32x4 o = ot[mt];
      o[0] *= rcp; o[1] *= rcp; o[2] *= rcp; o[3] *= rcp;
      *(f32x4*)(lds + ob + (orow + ((mt * 64 + g * 16) ^ osw))) = o;
    }
  }
  {
    const int qr = lane >> 2;
    const int c4 = lane & 3;
    float* op = Og + base + (size_t)(blkq + w * 16 + qr) * DH;
    const int orow = qr * 512;
    const int osw  = (qr & 7) << 4;
    #pragma unroll
    for (int u = 0; u < 8; ++u) {
      const int cb = c4 * 16 + u * 64;  // byte offset within the 512B row
      const f32x4 v = *(const f32x4*)(lds + ob + (orow + (cb ^ osw)));
      *(f32x4*)(op + (cb >> 2)) = v;
    }
  }
}

extern "C" void kernel_launch(void* const* d_in, const int* in_sizes, int n_in,
                              void* d_out, int out_size, void* d_ws, size_t ws_size,
                              hipStream_t stream) {
  const float* Kg = (const float*)d_in[0];  // "key"
  const float* Qg = (const float*)d_in[1];  // "query"
  const float* Vg = (const float*)d_in[2];  // "value"
  float* Og = (float*)d_out;
  attn_fwd<<<dim3(BH_N * (SEQ / BM)), dim3(256), 0, stream>>>(Kg, Qg, Vg, Og);
}

// Round 2
// 105.023 us; speedup vs baseline: 1.8688x; 1.8688x over previous
//
#include <hip/hip_runtime.h>
#include <hip/hip_bf16.h>
#include <cmath>

#define BH_N 32
#define SEQ  2048
#define DH   128
#define BM   256          // q rows per block (8 waves x 32)
#define KT   64           // keys per tile
#define NTILES (SEQ / KT) // 32

typedef __attribute__((ext_vector_type(4)))  float f32x4;
typedef __attribute__((ext_vector_type(16))) float f32x16;
typedef __attribute__((ext_vector_type(8)))  short bf16x8;
typedef __attribute__((ext_vector_type(4)))  unsigned int u32x4;

__device__ __forceinline__ unsigned cvtpk(float lo, float hi) {
  unsigned r;
  asm("v_cvt_pk_bf16_f32 %0, %1, %2" : "=v"(r) : "v"(lo), "v"(hi));
  return r;
}

// LDS: 2 buffers x 32KB. buf b at b*32768:
//   K_lds  [64 key][128 d] bf16 (256B rows), byte ^= (key&15)<<4   -> 2-way reads (free)
//   Vt_lds [128 d][64 key] bf16 (128B rows) at +16384, byte ^= (d&7)<<4
// Epilogue reuses [0,32768): per-wave 4KB O-transpose scratch.

__global__ __launch_bounds__(512, 2) void attn_fwd(
    const float* __restrict__ Kg, const float* __restrict__ Qg,
    const float* __restrict__ Vg, float* __restrict__ Og)
{
  __shared__ __align__(16) char lds[65536];
  constexpr float QSC = 0.08838834764831845f * 1.4426950408889634f; // 1/sqrt(128)*log2(e)

  const int t    = threadIdx.x;
  const int lane = t & 63;
  const int w    = t >> 6;       // 0..7
  const int hi   = lane >> 5;    // 0/1
  const int q31  = lane & 31;

  // XCD-aware remap: 8 consecutive logical blocks (one head) land on one XCD
  const int bid = blockIdx.x;
  const int lb  = (bid & 7) * 32 + (bid >> 3);
  const int bh  = lb >> 3;
  const int qb  = lb & 7;
  const int blkq = qb * BM;
  const size_t base = (size_t)bh * SEQ * DH;

  // ---- Q fragments (B-operand of St = K*Q^T), pre-scaled into exp2 domain
  bf16x8 qf[8];
  {
    const float* qp = Qg + base + (size_t)(blkq + w * 32 + q31) * DH + hi * 8;
    #pragma unroll
    for (int s = 0; s < 8; ++s) {
      const float4 a = *(const float4*)(qp + s * 16);
      const float4 b = *(const float4*)(qp + s * 16 + 4);
      u32x4 u = { cvtpk(a.x * QSC, a.y * QSC), cvtpk(a.z * QSC, a.w * QSC),
                  cvtpk(b.x * QSC, b.y * QSC), cvtpk(b.z * QSC, b.w * QSC) };
      qf[s] = __builtin_bit_cast(bf16x8, u);
    }
  }

  // ---- staging geometry (512 threads)
  const int kq = t >> 4;          // K: key row 0..31 (and +32)
  const int kd = (t & 15) * 8;    // K: d base
  const int vd = t & 127;         // V: d (row of Vt)
  const int vk = (t >> 7) * 16;   // V: key base (16 keys per thread)
  const float* kp0 = Kg + base + (size_t)kq * DH + kd;
  const float* vp0 = Vg + base + (size_t)vk * DH + vd;

  auto kv_load = [&](int tile2, float4* kf4, float* vv) {
    const float* kp = kp0 + (size_t)tile2 * (KT * DH);
    kf4[0] = *(const float4*)kp;
    kf4[1] = *(const float4*)(kp + 4);
    kf4[2] = *(const float4*)(kp + 32 * DH);
    kf4[3] = *(const float4*)(kp + 32 * DH + 4);
    const float* vp = vp0 + (size_t)tile2 * (KT * DH);
    #pragma unroll
    for (int j = 0; j < 16; ++j) vv[j] = vp[j * DH];
  };
  auto kv_write = [&](char* bb, const float4* kf4, const float* vv) {
    #pragma unroll
    for (int i = 0; i < 2; ++i) {
      const int key = kq + i * 32;
      u32x4 u = { cvtpk(kf4[2*i].x, kf4[2*i].y), cvtpk(kf4[2*i].z, kf4[2*i].w),
                  cvtpk(kf4[2*i+1].x, kf4[2*i+1].y), cvtpk(kf4[2*i+1].z, kf4[2*i+1].w) };
      *(u32x4*)(bb + key * 256 + ((kd * 2) ^ ((key & 15) << 4))) = u;
    }
    u32x4 u0 = { cvtpk(vv[0], vv[1]),  cvtpk(vv[2], vv[3]),
                 cvtpk(vv[4], vv[5]),  cvtpk(vv[6], vv[7]) };
    u32x4 u1 = { cvtpk(vv[8], vv[9]),  cvtpk(vv[10], vv[11]),
                 cvtpk(vv[12], vv[13]), cvtpk(vv[14], vv[15]) };
    const int vsw = (vd & 7) << 4;
    *(u32x4*)(bb + 16384 + vd * 128 + ((vk * 2) ^ vsw)) = u0;
    *(u32x4*)(bb + 16384 + vd * 128 + ((vk * 2 + 16) ^ vsw)) = u1;
  };

  f32x16 ot[4];
  #pragma unroll
  for (int dt = 0; dt < 4; ++dt)
    #pragma unroll
    for (int r = 0; r < 16; ++r) ot[dt][r] = 0.f;

  float m_run = -INFINITY;
  float l_run = 0.f;

  // prologue: stage tile 0
  {
    float4 kf4[4]; float vv[16];
    kv_load(0, kf4, vv);
    kv_write(lds, kf4, vv);
  }
  __syncthreads();

  for (int tile = 0; tile < NTILES; ++tile) {
    char* cbp = lds + (tile & 1) * 32768;
    float4 kf4[4]; float vv[16];
    const bool pre = (tile + 1 < NTILES);
    if (pre) kv_load(tile + 1, kf4, vv);   // HBM latency hides under compute

    // ---- St = K * Q^T : 2 tiles of 32key x 32q, 8 k-steps of 16
    f32x16 st[2];
    #pragma unroll
    for (int kt = 0; kt < 2; ++kt)
      #pragma unroll
      for (int r = 0; r < 16; ++r) st[kt][r] = 0.f;
    #pragma unroll
    for (int kt = 0; kt < 2; ++kt) {
      const int row = kt * 32 + q31;
      const int ksw = (row & 15) << 4;
      char* rb = cbp + row * 256;
      #pragma unroll
      for (int ks = 0; ks < 8; ++ks) {
        const bf16x8 kf = *(const bf16x8*)(rb + ((ks * 32 + hi * 16) ^ ksw));
        st[kt] = __builtin_amdgcn_mfma_f32_32x32x16_bf16(kf, qf[ks], st[kt], 0, 0, 0);
      }
    }

    // ---- online softmax (exp2 domain); q = lane&31, halves reduce via xor 32
    float tm = st[0][0];
    #pragma unroll
    for (int kt = 0; kt < 2; ++kt)
      #pragma unroll
      for (int r = 0; r < 16; ++r) tm = fmaxf(tm, st[kt][r]);
    tm = fmaxf(tm, __shfl_xor(tm, 32));
    if (!__all(tm <= m_run + 8.0f)) {      // deferred rescale (T13)
      const float mnew = fmaxf(m_run, tm);
      const float rs   = exp2f(m_run - mnew);
      l_run *= rs;
      #pragma unroll
      for (int dt = 0; dt < 4; ++dt)
        #pragma unroll
        for (int r = 0; r < 16; ++r) ot[dt][r] *= rs;
      m_run = mnew;
    }
    float psum = 0.f;
    #pragma unroll
    for (int kt = 0; kt < 2; ++kt)
      #pragma unroll
      for (int r = 0; r < 16; ++r) {
        const float p = exp2f(st[kt][r] - m_run);
        st[kt][r] = p;
        psum += p;
      }
    psum += __shfl_xor(psum, 32);
    l_run += psum;

    // ---- P -> PV B-fragments, fully in-register (cvt_pk + permlane32_swap)
    bf16x8 pf[4];
    #pragma unroll
    for (int kt = 0; kt < 2; ++kt) {
      unsigned a0 = cvtpk(st[kt][0], st[kt][1]);
      unsigned b0 = cvtpk(st[kt][4], st[kt][5]);
      asm volatile("v_permlane32_swap_b32 %0, %1" : "+v"(a0), "+v"(b0));
      unsigned c0 = cvtpk(st[kt][2], st[kt][3]);
      unsigned d0 = cvtpk(st[kt][6], st[kt][7]);
      asm volatile("v_permlane32_swap_b32 %0, %1" : "+v"(c0), "+v"(d0));
      u32x4 ue = { a0, c0, b0, d0 };
      pf[2 * kt] = __builtin_bit_cast(bf16x8, ue);
      unsigned a1 = cvtpk(st[kt][8],  st[kt][9]);
      unsigned b1 = cvtpk(st[kt][12], st[kt][13]);
      asm volatile("v_permlane32_swap_b32 %0, %1" : "+v"(a1), "+v"(b1));
      unsigned c1 = cvtpk(st[kt][10], st[kt][11]);
      unsigned d1 = cvtpk(st[kt][14], st[kt][15]);
      asm volatile("v_permlane32_swap_b32 %0, %1" : "+v"(c1), "+v"(d1));
      u32x4 uo = { a1, c1, b1, d1 };
      pf[2 * kt + 1] = __builtin_bit_cast(bf16x8, uo);
    }

    // ---- Ot += Vt * P^T : 4 d-tiles x 4 key-steps
    #pragma unroll
    for (int ks = 0; ks < 4; ++ks)
      #pragma unroll
      for (int dt = 0; dt < 4; ++dt) {
        const int row = dt * 32 + q31;
        const bf16x8 vf = *(const bf16x8*)(cbp + 16384 + row * 128 +
                                           ((ks * 32 + hi * 16) ^ ((row & 7) << 4)));
        ot[dt] = __builtin_amdgcn_mfma_f32_32x32x16_bf16(vf, pf[ks], ot[dt], 0, 0, 0);
      }

    if (pre) kv_write(lds + ((tile + 1) & 1) * 32768, kf4, vv);
    __syncthreads();
  }

  // ---- epilogue: normalize, per-wave LDS transpose, coalesced f32x4 stores
  const float rcp = 1.0f / l_run;
  char* ep = lds + (w << 12);          // 4KB per wave: [32 q][32 d] f32
  const int qsw = (q31 & 7) << 4;
  const int qr  = lane >> 1;
  const int hf  = lane & 1;
  const int rsw = (qr & 7) << 4;
  float* orow = Og + base + (size_t)(blkq + w * 32) * DH;
  #pragma unroll
  for (int dt = 0; dt < 4; ++dt) {
    #pragma unroll
    for (int a = 0; a < 4; ++a) {
      f32x4 v = { ot[dt][4*a+0] * rcp, ot[dt][4*a+1] * rcp,
                  ot[dt][4*a+2] * rcp, ot[dt][4*a+3] * rcp };
      const int dl = 8 * a + 4 * hi;   // d within 32-chunk, 16B aligned
      *(f32x4*)(ep + q31 * 128 + ((dl * 4) ^ qsw)) = v;
    }
    float* op = orow + (size_t)qr * DH + dt * 32 + hf * 16;
    #pragma unroll
    for (int u = 0; u < 4; ++u) {
      const f32x4 v = *(const f32x4*)(ep + qr * 128 + ((hf * 64 + u * 16) ^ rsw));
      *(f32x4*)(op + u * 4) = v;
    }
    __syncthreads();   // cheap; keeps wave-private regions race-free across dt reuse
  }
}

extern "C" void kernel_launch(void* const* d_in, const int* in_sizes, int n_in,
                              void* d_out, int out_size, void* d_ws, size_t ws_size,
                              hipStream_t stream) {
  const float* Kg = (const float*)d_in[0];  // "key"
  const float* Qg = (const float*)d_in[1];  // "query"
  const float* Vg = (const float*)d_in[2];  // "value"
  float* Og = (float*)d_out;
  attn_fwd<<<dim3(BH_N * (SEQ / BM)), dim3(512), 0, stream>>>(Kg, Qg, Vg, Og);
}

// Round 3
// 101.435 us; speedup vs baseline: 1.9349x; 1.0354x over previous
//
#include <hip/hip_runtime.h>
#include <hip/hip_bf16.h>
#include <cmath>

#define BH_N 32
#define SEQ  2048
#define DH   128
#define BM   256          // q rows per block (8 waves x 32)
#define KT   128          // keys per tile
#define NTILES (SEQ / KT) // 16

typedef __attribute__((ext_vector_type(4)))  float f32x4;
typedef __attribute__((ext_vector_type(16))) float f32x16;
typedef __attribute__((ext_vector_type(8)))  short bf16x8;
typedef __attribute__((ext_vector_type(4)))  unsigned int u32x4;

__device__ __forceinline__ unsigned cvtpk(float lo, float hi) {
  unsigned r;
  asm("v_cvt_pk_bf16_f32 %0, %1, %2" : "=v"(r) : "v"(lo), "v"(hi));
  return r;
}

// LDS: 2 buffers x 64KB at b*65536:
//   K_lds  [128 key][128 d] bf16 (256B rows), byte ^= (key&15)<<4
//   Vt_lds [128 d][128 key] bf16 (256B rows) at +32768, byte ^= (d&15)<<4
// Epilogue reuses [0,32768): per-wave 4KB O-transpose scratch.

__global__ __launch_bounds__(512, 2) void attn_fwd(
    const float* __restrict__ Kg, const float* __restrict__ Qg,
    const float* __restrict__ Vg, float* __restrict__ Og)
{
  __shared__ __align__(16) char lds[131072];
  constexpr float QSC = 0.08838834764831845f * 1.4426950408889634f; // 1/sqrt(128)*log2(e)

  const int t    = threadIdx.x;
  const int lane = t & 63;
  const int w    = t >> 6;       // 0..7
  const int hi   = lane >> 5;    // 0/1
  const int q31  = lane & 31;

  // XCD-aware remap: 8 consecutive logical blocks (one head) land on one XCD
  const int bid = blockIdx.x;
  const int lb  = (bid & 7) * 32 + (bid >> 3);
  const int bh  = lb >> 3;
  const int qb  = lb & 7;
  const int blkq = qb * BM;
  const size_t base = (size_t)bh * SEQ * DH;

  // ---- Q fragments (B-operand of St = K*Q^T), pre-scaled into exp2 domain
  bf16x8 qf[8];
  {
    const float* qp = Qg + base + (size_t)(blkq + w * 32 + q31) * DH + hi * 8;
    #pragma unroll
    for (int s = 0; s < 8; ++s) {
      const float4 a = *(const float4*)(qp + s * 16);
      const float4 b = *(const float4*)(qp + s * 16 + 4);
      u32x4 u = { cvtpk(a.x * QSC, a.y * QSC), cvtpk(a.z * QSC, a.w * QSC),
                  cvtpk(b.x * QSC, b.y * QSC), cvtpk(b.z * QSC, b.w * QSC) };
      qf[s] = __builtin_bit_cast(bf16x8, u);
    }
  }

  // ---- staging geometry (512 threads)
  const int kq  = t >> 4;          // K: key row 0..31 (+32*i)
  const int kd  = (t & 15) * 8;    // K: d base
  const int vd4 = (t & 31) * 4;    // V: d base (4 Vt rows per thread)
  const int vk8 = (t >> 5) * 8;    // V: key base (8 keys per thread)
  const float* kp0 = Kg + base + (size_t)kq * DH + kd;
  const float* vp0 = Vg + base + (size_t)vk8 * DH + vd4;

  auto k_load = [&](int tile, float4* kf4) {
    const float* kp = kp0 + (size_t)tile * (KT * DH);
    #pragma unroll
    for (int i = 0; i < 4; ++i) {
      kf4[2*i]   = *(const float4*)(kp + (size_t)i * 32 * DH);
      kf4[2*i+1] = *(const float4*)(kp + (size_t)i * 32 * DH + 4);
    }
  };
  auto k_write = [&](char* bb, const float4* kf4) {
    #pragma unroll
    for (int i = 0; i < 4; ++i) {
      const int key = kq + i * 32;
      u32x4 u = { cvtpk(kf4[2*i].x, kf4[2*i].y),   cvtpk(kf4[2*i].z, kf4[2*i].w),
                  cvtpk(kf4[2*i+1].x, kf4[2*i+1].y), cvtpk(kf4[2*i+1].z, kf4[2*i+1].w) };
      *(u32x4*)(bb + key * 256 + ((kd * 2) ^ ((key & 15) << 4))) = u;
    }
  };
  auto v_load = [&](int tile, float4* vv4) {
    const float* vp = vp0 + (size_t)tile * (KT * DH);
    #pragma unroll
    for (int j = 0; j < 8; ++j) vv4[j] = *(const float4*)(vp + (size_t)j * DH);
  };
  auto v_write = [&](char* bb, const float4* vv4) {
    #pragma unroll
    for (int r = 0; r < 4; ++r) {
      const int row = vd4 + r;
      const float* f = (const float*)vv4;   // vv4[j][r] = f[4*j + r]
      u32x4 u = { cvtpk(vv4[0][r], vv4[1][r]), cvtpk(vv4[2][r], vv4[3][r]),
                  cvtpk(vv4[4][r], vv4[5][r]), cvtpk(vv4[6][r], vv4[7][r]) };
      (void)f;
      *(u32x4*)(bb + 32768 + row * 256 + ((vk8 * 2) ^ ((row & 15) << 4))) = u;
    }
  };

  f32x16 ot[4];
  #pragma unroll
  for (int dt = 0; dt < 4; ++dt)
    #pragma unroll
    for (int r = 0; r < 16; ++r) ot[dt][r] = 0.f;

  float m_run = -INFINITY;
  float l_run = 0.f;

  // prologue: stage tile 0 into buf0
  {
    float4 kf4[8], vv4[8];
    k_load(0, kf4); v_load(0, vv4);
    k_write(lds, kf4); v_write(lds, vv4);
  }
  __syncthreads();

  f32x16 st[2];
  bf16x8 pfA[4], pfB[4];

  // ---- QK half-pass: 2 key-subtiles (32 keys each) starting at key krow0
  auto qk_pass = [&](const char* cbp, int krow0) {
    #pragma unroll
    for (int kt = 0; kt < 2; ++kt)
      #pragma unroll
      for (int r = 0; r < 16; ++r) st[kt][r] = 0.f;
    __builtin_amdgcn_s_setprio(1);
    #pragma unroll
    for (int kt = 0; kt < 2; ++kt) {
      const int row = krow0 + kt * 32 + q31;
      const int ksw = (row & 15) << 4;
      const char* rb = cbp + row * 256;
      #pragma unroll
      for (int ks = 0; ks < 8; ++ks) {
        const bf16x8 kf = *(const bf16x8*)(rb + ((ks * 32 + hi * 16) ^ ksw));
        st[kt] = __builtin_amdgcn_mfma_f32_32x32x16_bf16(kf, qf[ks], st[kt], 0, 0, 0);
      }
    }
    __builtin_amdgcn_s_setprio(0);
  };

  // ---- online softmax over st[0..1], emit pf[0..3]
  auto softmax_pack = [&](bf16x8* pf) {
    float tm = st[0][0];
    #pragma unroll
    for (int kt = 0; kt < 2; ++kt)
      #pragma unroll
      for (int r = 0; r < 16; ++r) tm = fmaxf(tm, st[kt][r]);
    tm = fmaxf(tm, __shfl_xor(tm, 32));
    if (!__all(tm <= m_run + 8.0f)) {      // deferred rescale (T13)
      const float mnew = fmaxf(m_run, tm);
      const float rs   = exp2f(m_run - mnew);
      l_run *= rs;
      #pragma unroll
      for (int dt = 0; dt < 4; ++dt)
        #pragma unroll
        for (int r = 0; r < 16; ++r) ot[dt][r] *= rs;
      m_run = mnew;
    }
    float psum = 0.f;
    #pragma unroll
    for (int kt = 0; kt < 2; ++kt)
      #pragma unroll
      for (int r = 0; r < 16; ++r) {
        const float p = exp2f(st[kt][r] - m_run);
        st[kt][r] = p;
        psum += p;
      }
    psum += __shfl_xor(psum, 32);
    l_run += psum;
    // P -> PV B-fragments, in-register (cvt_pk + permlane32_swap)
    #pragma unroll
    for (int kt = 0; kt < 2; ++kt) {
      unsigned a0 = cvtpk(st[kt][0], st[kt][1]);
      unsigned b0 = cvtpk(st[kt][4], st[kt][5]);
      asm volatile("v_permlane32_swap_b32 %0, %1" : "+v"(a0), "+v"(b0));
      unsigned c0 = cvtpk(st[kt][2], st[kt][3]);
      unsigned d0 = cvtpk(st[kt][6], st[kt][7]);
      asm volatile("v_permlane32_swap_b32 %0, %1" : "+v"(c0), "+v"(d0));
      u32x4 ue = { a0, c0, b0, d0 };
      pf[2 * kt] = __builtin_bit_cast(bf16x8, ue);
      unsigned a1 = cvtpk(st[kt][8],  st[kt][9]);
      unsigned b1 = cvtpk(st[kt][12], st[kt][13]);
      asm volatile("v_permlane32_swap_b32 %0, %1" : "+v"(a1), "+v"(b1));
      unsigned c1 = cvtpk(st[kt][10], st[kt][11]);
      unsigned d1 = cvtpk(st[kt][14], st[kt][15]);
      asm volatile("v_permlane32_swap_b32 %0, %1" : "+v"(c1), "+v"(d1));
      u32x4 uo = { a1, c1, b1, d1 };
      pf[2 * kt + 1] = __builtin_bit_cast(bf16x8, uo);
    }
  };

  // ---- PV half-pass: 4 key-slices of 16 starting at byte slot ks0*32
  auto pv_pass = [&](const char* cbp, int ks0, const bf16x8* pf) {
    __builtin_amdgcn_s_setprio(1);
    #pragma unroll
    for (int ks = 0; ks < 4; ++ks)
      #pragma unroll
      for (int dt = 0; dt < 4; ++dt) {
        const int row = dt * 32 + q31;
        const bf16x8 vf = *(const bf16x8*)(cbp + 32768 + row * 256 +
                                           (((ks0 + ks) * 32 + hi * 16) ^ ((row & 15) << 4)));
        ot[dt] = __builtin_amdgcn_mfma_f32_32x32x16_bf16(vf, pf[ks], ot[dt], 0, 0, 0);
      }
    __builtin_amdgcn_s_setprio(0);
  };

  for (int tile = 0; tile < NTILES; ++tile) {
    char* cbp = lds + (tile & 1) * 65536;
    char* nbp = lds + ((tile + 1) & 1) * 65536;
    const bool pre = (tile + 1 < NTILES);
    float4 kf4[8], vv4[8];

    if (pre) k_load(tile + 1, kf4);     // HBM latency hides under QK+softmax
    qk_pass(cbp, 0);                    // keys 0..63
    softmax_pack(pfA);
    if (pre) k_write(nbp, kf4);         // other buffer: legal before barrier
    if (pre) v_load(tile + 1, vv4);
    qk_pass(cbp, 64);                   // keys 64..127 (independent of smA)
    pv_pass(cbp, 0, pfA);
    softmax_pack(pfB);
    if (pre) v_write(nbp, vv4);
    pv_pass(cbp, 4, pfB);
    __syncthreads();
  }

  // ---- epilogue: normalize, per-wave LDS transpose, coalesced f32x4 stores
  const float rcp = 1.0f / l_run;
  char* ep = lds + (w << 12);          // 4KB per wave: [32 q][32 d] f32
  const int qsw = (q31 & 7) << 4;
  const int qr  = lane >> 1;
  const int hf  = lane & 1;
  const int rsw = (qr & 7) << 4;
  float* orow = Og + base + (size_t)(blkq + w * 32) * DH;
  #pragma unroll
  for (int dt = 0; dt < 4; ++dt) {
    #pragma unroll
    for (int a = 0; a < 4; ++a) {
      f32x4 v = { ot[dt][4*a+0] * rcp, ot[dt][4*a+1] * rcp,
                  ot[dt][4*a+2] * rcp, ot[dt][4*a+3] * rcp };
      const int dl = 8 * a + 4 * hi;   // d within 32-chunk, 16B aligned
      *(f32x4*)(ep + q31 * 128 + ((dl * 4) ^ qsw)) = v;
    }
    float* op = orow + (size_t)qr * DH + dt * 32 + hf * 16;
    #pragma unroll
    for (int u = 0; u < 4; ++u) {
      const f32x4 v = *(const f32x4*)(ep + qr * 128 + ((hf * 64 + u * 16) ^ rsw));
      *(f32x4*)(op + u * 4) = v;
    }
    __syncthreads();
  }
}

extern "C" void kernel_launch(void* const* d_in, const int* in_sizes, int n_in,
                              void* d_out, int out_size, void* d_ws, size_t ws_size,
                              hipStream_t stream) {
  const float* Kg = (const float*)d_in[0];  // "key"
  const float* Qg = (const float*)d_in[1];  // "query"
  const float* Vg = (const float*)d_in[2];  // "value"
  float* Og = (float*)d_out;
  attn_fwd<<<dim3(BH_N * (SEQ / BM)), dim3(512), 0, stream>>>(Kg, Qg, Vg, Og);
}